// Round 4
// baseline (523.315 us; speedup 1.0000x reference)
//
#include <hip/hip_runtime.h>
#include <hip/hip_bf16.h>
#include <stdint.h>

#define BDIM 8192
#define HDIM 2048
#define KDIM 4096   // IN + H
#define NDIM 6144   // 3 * H

using f32x16 = __attribute__((ext_vector_type(16))) float;
using bf16x8 = __attribute__((ext_vector_type(8))) short;
using short8 = __attribute__((ext_vector_type(8))) short;

__device__ __forceinline__ uint16_t f2bf(float f) {
    union { float f; uint32_t u; } v;
    v.f = f;
    uint32_t r = v.u + 0x7fffu + ((v.u >> 16) & 1u);  // RNE
    return (uint16_t)(r >> 16);
}

__device__ __forceinline__ float bf2f(uint16_t u) {
    union { uint32_t u; float f; } v;
    v.u = ((uint32_t)u) << 16;
    return v.f;
}

__device__ __forceinline__ float fast_sigmoid(float x) {
    return 1.0f / (1.0f + __expf(-x));
}

__device__ __forceinline__ float fast_tanh(float x) {
    float ax = fabsf(x);
    float t = __expf(-2.0f * ax);
    float r = (1.0f - t) / (1.0f + t);
    return copysignf(r, x);
}

// ---------------- fused conversion kernel ----------------
// chunks [0, XH_CHUNKS): xh = concat(x,h) -> bf16 [8192][4096]
// chunks [XH_CHUNKS, XH_CHUNKS+W_CHUNKS): Wb = [W_f;W_o;W_c] -> bf16 [6144][4096]
#define XH_CHUNKS ((int64_t)BDIM * KDIM / 4)
#define W_CHUNKS  ((int64_t)3 * HDIM * KDIM / 4)

__global__ void cvt_all_kernel(const float* __restrict__ x,
                               const float* __restrict__ h,
                               const float* __restrict__ Wf,
                               const float* __restrict__ Wo,
                               const float* __restrict__ Wc,
                               uint16_t* __restrict__ xh,
                               uint16_t* __restrict__ Wb) {
    const int64_t total = XH_CHUNKS + W_CHUNKS;
    for (int64_t i = (int64_t)blockIdx.x * blockDim.x + threadIdx.x; i < total;
         i += (int64_t)gridDim.x * blockDim.x) {
        float4 v;
        uint16_t* dst;
        if (i < XH_CHUNKS) {
            int64_t e = i << 2;
            int b = (int)(e >> 12);
            int k = (int)(e & 4095);
            if (k < 2048) v = *(const float4*)(x + (int64_t)b * 2048 + k);
            else          v = *(const float4*)(h + (int64_t)b * 2048 + (k - 2048));
            dst = xh + e;
        } else {
            int64_t e = (i - XH_CHUNKS) << 2;
            const int64_t per_gate = (int64_t)HDIM * KDIM;
            int gate = (int)(e / per_gate);
            int64_t rem = e - (int64_t)gate * per_gate;
            const float* src = (gate == 0) ? Wf : (gate == 1) ? Wo : Wc;
            v = *(const float4*)(src + rem);
            dst = Wb + e;
        }
        ushort4 o;
        o.x = f2bf(v.x); o.y = f2bf(v.y); o.z = f2bf(v.z); o.w = f2bf(v.w);
        *(ushort4*)dst = o;
    }
}

// ---------------- 256x256 8-phase GEMM, 32x32x16 MFMA ----------------
// A: [8192][4096] bf16, Wb: [6144][4096] bf16 (B^T), G out: [8192][6144] bf16
// 8 waves (2M x 4N), per-wave C = 128x64 = 4x2 frags of 32x32. BK=64.
// LDS ring: 8 slots of [128 rows][64 cols] bf16 (16 KiB each) = 128 KiB.
//   A slots: even tile h0->0 h1->1, odd tile h0->2 h1->3   (h = qm = mf-pair)
//   B slots: even tile h0->4 h1->5, odd tile h0->6 h1->7   (h = qn = nf)
// Phases per K-tile: P(0,0) reads A-h0(8)+B-h0(4); P(0,1) reads B-h1(4);
// P(1,0) reads A-h1(8); P(1,1) reads nothing. 24 ds_read_b128/K-tile/wave.
// Stage order: P1->s3, P2->s0, P3->s4, P4->s1, P5->s5, P6->s2, P7->s6, P8->s7
// vmcnt(4) at P4 completes {s6,s7,s3,s0}; at P8 completes {s4,s1,s5,s2}.
// Frag layouts (32x32x16 bf16): A/B: row/col = lane&31, k = (lane>>5)*8 + i.
// C/D: col = lane&31, row = (reg&3) + 8*(reg>>2) + 4*(lane>>5)  [m74/m101].

#define STAGE_A(slot, t, h) do { \
    _Pragma("unroll") for (int q_ = 0; q_ < 2; ++q_) { \
        const int r_ = s_row[q_]; \
        const uint16_t* src_ = A + (int64_t)(m0 + ((r_ >> 6) << 7) + ((h) << 6) + (r_ & 63)) * KDIM + ((t) << 6) + s_kc[q_]; \
        __builtin_amdgcn_global_load_lds((__attribute__((address_space(1))) void*)(src_), \
            (__attribute__((address_space(3))) void*)(&lds[slot][(q_ * 512 + tid) * 8]), 16, 0, 0); \
    } } while (0)

#define STAGE_B(slot, t, h) do { \
    _Pragma("unroll") for (int q_ = 0; q_ < 2; ++q_) { \
        const int r_ = s_row[q_]; \
        const uint16_t* src_ = Wb + (int64_t)(n0 + ((r_ >> 5) << 6) + ((h) << 5) + (r_ & 31)) * KDIM + ((t) << 6) + s_kc[q_]; \
        __builtin_amdgcn_global_load_lds((__attribute__((address_space(1))) void*)(src_), \
            (__attribute__((address_space(3))) void*)(&lds[slot][(q_ * 512 + tid) * 8]), 16, 0, 0); \
    } } while (0)

// read logical (slot, srow, kchunk[8-elem]) with swizzle
#define RD(slot, srow, kc) \
    (*(const bf16x8*)((const char*)(&lds[0][0]) + ((slot) * 16384) + ((srow) * 128) + ((((kc) ^ ((srow) & 7))) * 16)))

// A frags for quadrant qm of K-tile tp: aF[kstep][mf2]
#define RD_A32(tp, qm) do { \
    _Pragma("unroll") for (int kk = 0; kk < 4; ++kk) \
        _Pragma("unroll") for (int mf2 = 0; mf2 < 2; ++mf2) \
            aF[kk][mf2] = RD((((tp) & 1) << 1) + (qm), wm * 64 + mf2 * 32 + ln31, kk * 2 + hi); \
} while (0)

// B frags for nf=qn of K-tile tp: dst[kstep]
#define RD_B32(dst, tp, qn) do { \
    _Pragma("unroll") for (int kk = 0; kk < 4; ++kk) \
        dst[kk] = RD(4 + (((tp) & 1) << 1) + (qn), wn * 32 + ln31, kk * 2 + hi); \
} while (0)

#define MM32(qm, qn, bsrc) do { \
    _Pragma("unroll") for (int kk = 0; kk < 4; ++kk) \
        _Pragma("unroll") for (int mf2 = 0; mf2 < 2; ++mf2) \
            acc[(qm) * 2 + mf2][(qn)] = __builtin_amdgcn_mfma_f32_32x32x16_bf16( \
                aF[kk][mf2], bsrc[kk], acc[(qm) * 2 + mf2][(qn)], 0, 0, 0); \
} while (0)

#define PHX(READS, STAGE, MFMAS, WAITC) do { \
    asm volatile("" ::: "memory"); \
    READS; \
    STAGE; \
    asm volatile("" ::: "memory"); \
    __builtin_amdgcn_s_barrier(); \
    asm volatile("s_waitcnt lgkmcnt(0)" ::: "memory"); \
    __builtin_amdgcn_s_setprio(1); \
    MFMAS; \
    __builtin_amdgcn_s_setprio(0); \
    WAITC; \
    __builtin_amdgcn_s_barrier(); \
} while (0)

#define WC4 asm volatile("s_waitcnt vmcnt(4)" ::: "memory")
#define WC0 asm volatile("s_waitcnt vmcnt(0)" ::: "memory")

__global__ __launch_bounds__(512, 2) void lstm_gemm8p_kernel(
    const uint16_t* __restrict__ A,
    const uint16_t* __restrict__ Wb,
    uint16_t* __restrict__ G) {
    __shared__ uint16_t lds[8][8192];  // 128 KiB

    const int tid = threadIdx.x;
    const int lane = tid & 63;
    const int ln31 = lane & 31;
    const int hi = lane >> 5;
    const int wid = tid >> 6;
    const int wm = wid >> 2;   // 0..1
    const int wn = wid & 3;    // 0..3

    // XCD-aware swizzle: 768 blocks, 768 % 8 == 0 -> simple bijection
    const int bid = blockIdx.x;
    const int swz = (bid & 7) * 96 + (bid >> 3);
    const int mb = swz / 24;
    const int nb = swz - mb * 24;
    const int m0 = mb << 8;
    const int n0 = nb << 8;

    // staging constants: chunk = q*512 + tid -> row, swizzled k-chunk
    int s_row[2], s_kc[2];
#pragma unroll
    for (int q_ = 0; q_ < 2; ++q_) {
        const int chunk = q_ * 512 + tid;
        const int r_ = chunk >> 3;
        const int c_ = chunk & 7;
        s_row[q_] = r_;
        s_kc[q_] = (c_ ^ (r_ & 7)) * 8;  // element offset
    }

    f32x16 acc[4][2] = {};
    bf16x8 aF[4][2];
    bf16x8 bF0[4];
    bf16x8 bF1[4];

    // prologue: t0 full (s0,s4,s1,s5), t1 h0 (s2,s6), t1 h1 B (s7).
    // s3 (t1 h1 A) is staged in-loop at P1 -> loop is uniform from i=0.
    STAGE_A(0, 0, 0); STAGE_B(4, 0, 0);
    STAGE_A(1, 0, 1); STAGE_B(5, 0, 1);
    STAGE_A(2, 1, 0); STAGE_B(6, 1, 0);
    STAGE_B(7, 1, 1);
    WC4;  // completes s0,s4,s1,s5,s2 ; leaves s6,s7 in flight
    __builtin_amdgcn_s_barrier();

    // 64 K-tiles, 2 per iteration; i=31 is the peeled tail
    for (int i = 0; i < 31; ++i) {
        const int t0 = 2 * i;
        const int t1 = t0 + 1, t2 = t0 + 2, t3 = t0 + 3;
        PHX(RD_A32(t0, 0); RD_B32(bF0, t0, 0), STAGE_A(3, t1, 1), MM32(0, 0, bF0), );
        PHX(RD_B32(bF1, t0, 1),                STAGE_A(0, t2, 0), MM32(0, 1, bF1), );
        PHX(RD_A32(t0, 1),                     STAGE_B(4, t2, 0), MM32(1, 0, bF0), );
        PHX(;,                                 STAGE_A(1, t2, 1), MM32(1, 1, bF1), WC4);
        PHX(RD_A32(t1, 0); RD_B32(bF0, t1, 0), STAGE_B(5, t2, 1), MM32(0, 0, bF0), );
        PHX(RD_B32(bF1, t1, 1),                STAGE_A(2, t3, 0), MM32(0, 1, bF1), );
        PHX(RD_A32(t1, 1),                     STAGE_B(6, t3, 0), MM32(1, 0, bF0), );
        PHX(;,                                 STAGE_B(7, t3, 1), MM32(1, 1, bF1), WC4);
    }
    // tail: t0=62, t1=63; only the s3 stage remains in-range
    PHX(RD_A32(62, 0); RD_B32(bF0, 62, 0), STAGE_A(3, 63, 1), MM32(0, 0, bF0), );
    PHX(RD_B32(bF1, 62, 1),                ;,                 MM32(0, 1, bF1), );
    PHX(RD_A32(62, 1),                     ;,                 MM32(1, 0, bF0), );
    PHX(;,                                 ;,                 MM32(1, 1, bF1), WC0);
    PHX(RD_A32(63, 0); RD_B32(bF0, 63, 0), ;,                 MM32(0, 0, bF0), );
    PHX(RD_B32(bF1, 63, 1),                ;,                 MM32(0, 1, bF1), );
    PHX(RD_A32(63, 1),                     ;,                 MM32(1, 0, bF0), );
    PHX(;,                                 ;,                 MM32(1, 1, bF1), );

    // C-write: 32x32 D layout col = lane&31, row = (r&3) + 8*(r>>2) + 4*hi
#pragma unroll
    for (int Mf = 0; Mf < 4; ++Mf) {
#pragma unroll
        for (int nf = 0; nf < 2; ++nf) {
            const int n = n0 + wn * 64 + nf * 32 + ln31;
            const int mbase = m0 + wm * 128 + Mf * 32 + hi * 4;
#pragma unroll
            for (int r = 0; r < 16; ++r) {
                const int m = mbase + (r & 3) + 8 * (r >> 2);
                G[(int64_t)m * NDIM + n] = f2bf(acc[Mf][nf][r]);
            }
        }
    }
}

// ---------------- LSTM elementwise epilogue ----------------

__global__ void lstm_epi_kernel(const uint16_t* __restrict__ G,
                                const float* __restrict__ c_prev,
                                const float* __restrict__ b_f,
                                const float* __restrict__ b_o,
                                const float* __restrict__ b_c,
                                float* __restrict__ h_out,
                                float* __restrict__ c_out) {
    const int64_t total = (int64_t)BDIM * HDIM / 8;
    for (int64_t i = (int64_t)blockIdx.x * blockDim.x + threadIdx.x; i < total;
         i += (int64_t)gridDim.x * blockDim.x) {
        const int64_t e = i << 3;
        const int m = (int)(e >> 11);
        const int n = (int)(e & 2047);
        const int64_t gb = (int64_t)m * NDIM + n;
        const short8 fv = *(const short8*)(G + gb);
        const short8 ov = *(const short8*)(G + gb + HDIM);
        const short8 cv = *(const short8*)(G + gb + 2 * HDIM);
        const float4 cp0 = *(const float4*)(c_prev + (int64_t)m * HDIM + n);
        const float4 cp1 = *(const float4*)(c_prev + (int64_t)m * HDIM + n + 4);
        float cp[8] = {cp0.x, cp0.y, cp0.z, cp0.w, cp1.x, cp1.y, cp1.z, cp1.w};
        float hr[8], cr[8];
#pragma unroll
        for (int j = 0; j < 8; ++j) {
            const float fpre = bf2f((uint16_t)fv[j]) + b_f[n + j];
            const float opre = bf2f((uint16_t)ov[j]) + b_o[n + j];
            const float cpre = bf2f((uint16_t)cv[j]) + b_c[n + j];
            const float ft = fast_sigmoid(fpre);
            const float ot = fast_sigmoid(opre);
            const float ch = fast_tanh(cpre);
            const float ct = ft * cp[j] + (1.0f - ft) * ch;
            hr[j] = ot * fast_tanh(ct);
            cr[j] = ct;
        }
        float4 h0 = {hr[0], hr[1], hr[2], hr[3]};
        float4 h1 = {hr[4], hr[5], hr[6], hr[7]};
        float4 c0 = {cr[0], cr[1], cr[2], cr[3]};
        float4 c1 = {cr[4], cr[5], cr[6], cr[7]};
        *(float4*)(h_out + (int64_t)m * HDIM + n) = h0;
        *(float4*)(h_out + (int64_t)m * HDIM + n + 4) = h1;
        *(float4*)(c_out + (int64_t)m * HDIM + n) = c0;
        *(float4*)(c_out + (int64_t)m * HDIM + n + 4) = c1;
    }
}

extern "C" void kernel_launch(void* const* d_in, const int* in_sizes, int n_in,
                              void* d_out, int out_size, void* d_ws, size_t ws_size,
                              hipStream_t stream) {
    const float* x_t   = (const float*)d_in[0];
    const float* h_t_1 = (const float*)d_in[1];
    const float* c_t_1 = (const float*)d_in[2];
    const float* W_f   = (const float*)d_in[3];
    const float* b_f   = (const float*)d_in[4];
    const float* W_o   = (const float*)d_in[5];
    const float* b_o   = (const float*)d_in[6];
    const float* W_c   = (const float*)d_in[7];
    const float* b_c   = (const float*)d_in[8];

    uint16_t* xh  = (uint16_t*)d_ws;                            // 64 MiB
    uint16_t* Wbf = xh + (size_t)BDIM * KDIM;                   // 48 MiB
    uint16_t* G   = Wbf + (size_t)NDIM * KDIM;                  // 96 MiB

    float* h_out = (float*)d_out;
    float* c_out = h_out + (size_t)BDIM * HDIM;

    cvt_all_kernel<<<2048, 256, 0, stream>>>(x_t, h_t_1, W_f, W_o, W_c, xh, Wbf);
    lstm_gemm8p_kernel<<<768, 512, 0, stream>>>(xh, Wbf, G);
    lstm_epi_kernel<<<2048, 256, 0, stream>>>(G, c_t_1, b_f, b_o, b_c,
                                              h_out, c_out);
}

// Round 5
// 473.572 us; speedup vs baseline: 1.1050x; 1.1050x over previous
//
#include <hip/hip_runtime.h>
#include <hip/hip_bf16.h>
#include <stdint.h>

#define BDIM 8192
#define HDIM 2048
#define KDIM 4096   // IN + H
#define NDIM 6144   // 3 * H

using f32x4  = __attribute__((ext_vector_type(4))) float;
using bf16x8 = __attribute__((ext_vector_type(8))) short;
using short8 = __attribute__((ext_vector_type(8))) short;

__device__ __forceinline__ uint16_t f2bf(float f) {
    union { float f; uint32_t u; } v;
    v.f = f;
    uint32_t r = v.u + 0x7fffu + ((v.u >> 16) & 1u);  // RNE
    return (uint16_t)(r >> 16);
}

__device__ __forceinline__ float bf2f(uint16_t u) {
    union { uint32_t u; float f; } v;
    v.u = ((uint32_t)u) << 16;
    return v.f;
}

__device__ __forceinline__ float fast_sigmoid(float x) {
    return 1.0f / (1.0f + __expf(-x));
}

__device__ __forceinline__ float fast_tanh(float x) {
    float ax = fabsf(x);
    float t = __expf(-2.0f * ax);
    float r = (1.0f - t) / (1.0f + t);
    return copysignf(r, x);
}

// ---------------- fused conversion kernel ----------------
#define XH_CHUNKS ((int64_t)BDIM * KDIM / 4)
#define W_CHUNKS  ((int64_t)3 * HDIM * KDIM / 4)

__global__ void cvt_all_kernel(const float* __restrict__ x,
                               const float* __restrict__ h,
                               const float* __restrict__ Wf,
                               const float* __restrict__ Wo,
                               const float* __restrict__ Wc,
                               uint16_t* __restrict__ xh,
                               uint16_t* __restrict__ Wb) {
    const int64_t total = XH_CHUNKS + W_CHUNKS;
    for (int64_t i = (int64_t)blockIdx.x * blockDim.x + threadIdx.x; i < total;
         i += (int64_t)gridDim.x * blockDim.x) {
        float4 v;
        uint16_t* dst;
        if (i < XH_CHUNKS) {
            int64_t e = i << 2;
            int b = (int)(e >> 12);
            int k = (int)(e & 4095);
            if (k < 2048) v = *(const float4*)(x + (int64_t)b * 2048 + k);
            else          v = *(const float4*)(h + (int64_t)b * 2048 + (k - 2048));
            dst = xh + e;
        } else {
            int64_t e = (i - XH_CHUNKS) << 2;
            const int64_t per_gate = (int64_t)HDIM * KDIM;
            int gate = (int)(e / per_gate);
            int64_t rem = e - (int64_t)gate * per_gate;
            const float* src = (gate == 0) ? Wf : (gate == 1) ? Wo : Wc;
            v = *(const float4*)(src + rem);
            dst = Wb + e;
        }
        ushort4 o;
        o.x = f2bf(v.x); o.y = f2bf(v.y); o.z = f2bf(v.z); o.w = f2bf(v.w);
        *(ushort4*)dst = o;
    }
}

// ---------------- 256x256 8-phase GEMM (16x16x32, balanced reads) --------
// A: [8192][4096] bf16, Wb: [6144][4096] bf16 (B^T), G out: [8192][6144] bf16
// 8 waves (2M x 4N), per-wave C = 128x64. BK=64.
// LDS ring: 8 slots of [128 rows][64 cols] bf16 (16 KiB each) = 128 KiB.
//   A slots: even tile h0->0 h1->1, odd tile h0->2 h1->3
//   B slots: even tile h0->4 h1->5, odd tile h0->6 h1->7
// Balanced phase reads (8/4/8/4 per phase, 24 b128/K-tile/wave):
//   P1: aF(t0,h0)        P2: bF1(t0,h1)   P3: aF(t0,h1)   P4: bF0(t1,h0)
//   P5: aF(t1,h0)        P6: bF1(t1,h1)   P7: aF(t1,h1)   P8: bF0(t2,h0)
// (bF0 of tile t is read one phase early, in the previous tile's P(1,1).)
// Stage order: P1->s3, P2->s0, P3->s4, P4->s1, P5->s5, P6->s2, P7->s6, P8->s7
// Waits: WC6@P3-end, WC4@P4-end, WC6@P7-end, WC4@P8-end.
// Steady-state outstanding entering an iteration = {s6,s7}. Coverage:
//   P3-WC6 completes s6^,s7^ (prev P7/P8)  -> P4 reads s6^, P6 reads s7^ OK
//   P4-WC4 completes s3,s0                 -> P7 reads s3; next-P1 reads s0 OK
//   P7-WC6 completes s4,s1                 -> P8 reads s4; next-P3 reads s1 OK
//   P8-WC4 completes s5,s2                 -> next-P2 reads s5; next-P5 reads s2
// Every read is covered by a wave-local vmcnt wait placed BEFORE a barrier
// (cross-wave safe). Tail peeled with WC0.

#define STAGE_A(slot, t, h) do { \
    _Pragma("unroll") for (int q_ = 0; q_ < 2; ++q_) { \
        const int r_ = s_row[q_]; \
        const uint16_t* src_ = A + (int64_t)(m0 + ((r_ >> 6) << 7) + ((h) << 6) + (r_ & 63)) * KDIM + ((t) << 6) + s_kc[q_]; \
        __builtin_amdgcn_global_load_lds((__attribute__((address_space(1))) void*)(src_), \
            (__attribute__((address_space(3))) void*)(&lds[slot][(q_ * 512 + tid) * 8]), 16, 0, 0); \
    } } while (0)

#define STAGE_B(slot, t, h) do { \
    _Pragma("unroll") for (int q_ = 0; q_ < 2; ++q_) { \
        const int r_ = s_row[q_]; \
        const uint16_t* src_ = Wb + (int64_t)(n0 + ((r_ >> 5) << 6) + ((h) << 5) + (r_ & 31)) * KDIM + ((t) << 6) + s_kc[q_]; \
        __builtin_amdgcn_global_load_lds((__attribute__((address_space(1))) void*)(src_), \
            (__attribute__((address_space(3))) void*)(&lds[slot][(q_ * 512 + tid) * 8]), 16, 0, 0); \
    } } while (0)

// read logical (slot, srow, kchunk) with swizzle
#define RD(slot, srow, kc) \
    (*(const bf16x8*)((const char*)(&lds[0][0]) + ((slot) * 16384) + ((srow) * 128) + ((((kc) ^ ((srow) & 7))) * 16)))

#define RD_A(tp, h) do { \
    _Pragma("unroll") for (int kk = 0; kk < 2; ++kk) \
        _Pragma("unroll") for (int mf = 0; mf < 4; ++mf) \
            aF[kk][mf] = RD((((tp) & 1) << 1) + (h), wm * 64 + mf * 16 + fr, kk * 4 + kg); \
} while (0)

#define RD_B(dst, tp, h) do { \
    _Pragma("unroll") for (int kk = 0; kk < 2; ++kk) \
        _Pragma("unroll") for (int nf = 0; nf < 2; ++nf) \
            dst[kk][nf] = RD(4 + (((tp) & 1) << 1) + (h), wn * 32 + nf * 16 + fr, kk * 4 + kg); \
} while (0)

#define MM(qm, qn, bsrc) do { \
    _Pragma("unroll") for (int kk = 0; kk < 2; ++kk) \
        _Pragma("unroll") for (int mf = 0; mf < 4; ++mf) \
            _Pragma("unroll") for (int nf = 0; nf < 2; ++nf) \
                acc[(qm) * 4 + mf][(qn) * 2 + nf] = __builtin_amdgcn_mfma_f32_16x16x32_bf16( \
                    aF[kk][mf], bsrc[kk][nf], acc[(qm) * 4 + mf][(qn) * 2 + nf], 0, 0, 0); \
} while (0)

#define PHX(READS, STAGE, MFMAS, WAITC) do { \
    asm volatile("" ::: "memory"); \
    READS; \
    STAGE; \
    asm volatile("" ::: "memory"); \
    __builtin_amdgcn_s_barrier(); \
    asm volatile("s_waitcnt lgkmcnt(0)" ::: "memory"); \
    __builtin_amdgcn_s_setprio(1); \
    MFMAS; \
    __builtin_amdgcn_s_setprio(0); \
    WAITC; \
    __builtin_amdgcn_s_barrier(); \
} while (0)

#define WC6 asm volatile("s_waitcnt vmcnt(6)" ::: "memory")
#define WC4 asm volatile("s_waitcnt vmcnt(4)" ::: "memory")
#define WC0 asm volatile("s_waitcnt vmcnt(0)" ::: "memory")

__global__ __launch_bounds__(512, 2) void lstm_gemm8p_kernel(
    const uint16_t* __restrict__ A,
    const uint16_t* __restrict__ Wb,
    uint16_t* __restrict__ G) {
    __shared__ uint16_t lds[8][8192];  // 128 KiB

    const int tid = threadIdx.x;
    const int lane = tid & 63;
    const int kg = lane >> 4;
    const int fr = lane & 15;
    const int wid = tid >> 6;
    const int wm = wid >> 2;   // 0..1
    const int wn = wid & 3;    // 0..3

    // XCD-aware swizzle: 768 blocks, 768 % 8 == 0 -> simple bijection
    const int bid = blockIdx.x;
    const int swz = (bid & 7) * 96 + (bid >> 3);
    const int mb = swz / 24;
    const int nb = swz - mb * 24;
    const int m0 = mb << 8;
    const int n0 = nb << 8;

    // staging constants: chunk = q*512 + tid -> row, swizzled k-chunk
    int s_row[2], s_kc[2];
#pragma unroll
    for (int q_ = 0; q_ < 2; ++q_) {
        const int chunk = q_ * 512 + tid;
        const int r_ = chunk >> 3;
        const int c_ = chunk & 7;
        s_row[q_] = r_;
        s_kc[q_] = (c_ ^ (r_ & 7)) * 8;  // element offset
    }

    f32x4 acc[8][4] = {};
    bf16x8 aF[2][4];
    bf16x8 bF0[2][2];
    bf16x8 bF1[2][2];

    // prologue: t0 full (s0,s4,s1,s5), t1 h0 (s2,s6), t1 h1 B (s7).
    STAGE_A(0, 0, 0); STAGE_B(4, 0, 0);
    STAGE_A(1, 0, 1); STAGE_B(5, 0, 1);
    STAGE_A(2, 1, 0); STAGE_B(6, 1, 0);
    STAGE_B(7, 1, 1);
    WC4;  // completes s0,s4,s1,s5,s2 ; leaves s6,s7 in flight
    __builtin_amdgcn_s_barrier();
    RD_B(bF0, 0, 0);  // pre-read B(t0,h0) from s4 (complete; all waves waited)

    // 64 K-tiles, 2 per iteration; i=31 is the peeled tail
    for (int i = 0; i < 31; ++i) {
        const int t0 = 2 * i;
        const int t1 = t0 + 1, t2 = t0 + 2, t3 = t0 + 3;
        PHX(RD_A(t0, 0),      STAGE_A(3, t1, 1), MM(0, 0, bF0), );
        PHX(RD_B(bF1, t0, 1), STAGE_A(0, t2, 0), MM(0, 1, bF1), );
        PHX(RD_A(t0, 1),      STAGE_B(4, t2, 0), MM(1, 0, bF0), WC6);
        PHX(RD_B(bF0, t1, 0), STAGE_A(1, t2, 1), MM(1, 1, bF1), WC4);
        PHX(RD_A(t1, 0),      STAGE_B(5, t2, 1), MM(0, 0, bF0), );
        PHX(RD_B(bF1, t1, 1), STAGE_A(2, t3, 0), MM(0, 1, bF1), );
        PHX(RD_A(t1, 1),      STAGE_B(6, t3, 0), MM(1, 0, bF0), WC6);
        PHX(RD_B(bF0, t2, 0), STAGE_B(7, t3, 1), MM(1, 1, bF1), WC4);
    }
    // tail: t0=62, t1=63; only the s3 stage remains in-range
    PHX(RD_A(62, 0),      STAGE_A(3, 63, 1), MM(0, 0, bF0), );
    PHX(RD_B(bF1, 62, 1), ;,                 MM(0, 1, bF1), );
    PHX(RD_A(62, 1),      ;,                 MM(1, 0, bF0), WC0);
    PHX(RD_B(bF0, 63, 0), ;,                 MM(1, 1, bF1), );
    PHX(RD_A(63, 0),      ;,                 MM(0, 0, bF0), );
    PHX(RD_B(bF1, 63, 1), ;,                 MM(0, 1, bF1), );
    PHX(RD_A(63, 1),      ;,                 MM(1, 0, bF0), );
    PHX(;,                ;,                 MM(1, 1, bF1), );

    // C-write: D layout col = lane&15, row = (lane>>4)*4 + j
#pragma unroll
    for (int mf = 0; mf < 8; ++mf) {
#pragma unroll
        for (int nf = 0; nf < 4; ++nf) {
            const int n = n0 + wn * 64 + nf * 16 + fr;
            const int64_t mbase = (int64_t)(m0 + wm * 128 + mf * 16 + kg * 4);
#pragma unroll
            for (int j = 0; j < 4; ++j) {
                G[(mbase + j) * NDIM + n] = f2bf(acc[mf][nf][j]);
            }
        }
    }
}

// ---------------- LSTM elementwise epilogue ----------------

__global__ void lstm_epi_kernel(const uint16_t* __restrict__ G,
                                const float* __restrict__ c_prev,
                                const float* __restrict__ b_f,
                                const float* __restrict__ b_o,
                                const float* __restrict__ b_c,
                                float* __restrict__ h_out,
                                float* __restrict__ c_out) {
    const int64_t total = (int64_t)BDIM * HDIM / 8;
    for (int64_t i = (int64_t)blockIdx.x * blockDim.x + threadIdx.x; i < total;
         i += (int64_t)gridDim.x * blockDim.x) {
        const int64_t e = i << 3;
        const int m = (int)(e >> 11);
        const int n = (int)(e & 2047);
        const int64_t gb = (int64_t)m * NDIM + n;
        const short8 fv = *(const short8*)(G + gb);
        const short8 ov = *(const short8*)(G + gb + HDIM);
        const short8 cv = *(const short8*)(G + gb + 2 * HDIM);
        const float4 cp0 = *(const float4*)(c_prev + (int64_t)m * HDIM + n);
        const float4 cp1 = *(const float4*)(c_prev + (int64_t)m * HDIM + n + 4);
        float cp[8] = {cp0.x, cp0.y, cp0.z, cp0.w, cp1.x, cp1.y, cp1.z, cp1.w};
        float hr[8], cr[8];
#pragma unroll
        for (int j = 0; j < 8; ++j) {
            const float fpre = bf2f((uint16_t)fv[j]) + b_f[n + j];
            const float opre = bf2f((uint16_t)ov[j]) + b_o[n + j];
            const float cpre = bf2f((uint16_t)cv[j]) + b_c[n + j];
            const float ft = fast_sigmoid(fpre);
            const float ot = fast_sigmoid(opre);
            const float ch = fast_tanh(cpre);
            const float ct = ft * cp[j] + (1.0f - ft) * ch;
            hr[j] = ot * fast_tanh(ct);
            cr[j] = ct;
        }
        float4 h0 = {hr[0], hr[1], hr[2], hr[3]};
        float4 h1 = {hr[4], hr[5], hr[6], hr[7]};
        float4 c0 = {cr[0], cr[1], cr[2], cr[3]};
        float4 c1 = {cr[4], cr[5], cr[6], cr[7]};
        *(float4*)(h_out + (int64_t)m * HDIM + n) = h0;
        *(float4*)(h_out + (int64_t)m * HDIM + n + 4) = h1;
        *(float4*)(c_out + (int64_t)m * HDIM + n) = c0;
        *(float4*)(c_out + (int64_t)m * HDIM + n + 4) = c1;
    }
}

extern "C" void kernel_launch(void* const* d_in, const int* in_sizes, int n_in,
                              void* d_out, int out_size, void* d_ws, size_t ws_size,
                              hipStream_t stream) {
    const float* x_t   = (const float*)d_in[0];
    const float* h_t_1 = (const float*)d_in[1];
    const float* c_t_1 = (const float*)d_in[2];
    const float* W_f   = (const float*)d_in[3];
    const float* b_f   = (const float*)d_in[4];
    const float* W_o   = (const float*)d_in[5];
    const float* b_o   = (const float*)d_in[6];
    const float* W_c   = (const float*)d_in[7];
    const float* b_c   = (const float*)d_in[8];

    uint16_t* xh  = (uint16_t*)d_ws;                            // 64 MiB
    uint16_t* Wbf = xh + (size_t)BDIM * KDIM;                   // 48 MiB
    uint16_t* G   = Wbf + (size_t)NDIM * KDIM;                  // 96 MiB

    float* h_out = (float*)d_out;
    float* c_out = h_out + (size_t)BDIM * HDIM;

    cvt_all_kernel<<<2048, 256, 0, stream>>>(x_t, h_t_1, W_f, W_o, W_c, xh, Wbf);
    lstm_gemm8p_kernel<<<768, 512, 0, stream>>>(xh, Wbf, G);
    lstm_epi_kernel<<<2048, 256, 0, stream>>>(G, c_t_1, b_f, b_o, b_c,
                                              h_out, c_out);
}

// Round 6
// 468.776 us; speedup vs baseline: 1.1163x; 1.0102x over previous
//
#include <hip/hip_runtime.h>
#include <hip/hip_bf16.h>
#include <stdint.h>

#define BDIM 8192
#define HDIM 2048
#define KDIM 4096   // IN + H
#define NDIM 6144   // 3 * H

using f32x4  = __attribute__((ext_vector_type(4))) float;
using bf16x8 = __attribute__((ext_vector_type(8))) short;
using short8 = __attribute__((ext_vector_type(8))) short;

__device__ __forceinline__ uint16_t f2bf(float f) {
    union { float f; uint32_t u; } v;
    v.f = f;
    uint32_t r = v.u + 0x7fffu + ((v.u >> 16) & 1u);  // RNE
    return (uint16_t)(r >> 16);
}

__device__ __forceinline__ float bf2f(uint16_t u) {
    union { uint32_t u; float f; } v;
    v.u = ((uint32_t)u) << 16;
    return v.f;
}

__device__ __forceinline__ float fast_sigmoid(float x) {
    return 1.0f / (1.0f + __expf(-x));
}

__device__ __forceinline__ float fast_tanh(float x) {
    float ax = fabsf(x);
    float t = __expf(-2.0f * ax);
    float r = (1.0f - t) / (1.0f + t);
    return copysignf(r, x);
}

// ---------------- fused conversion kernel ----------------
#define XH_CHUNKS ((int64_t)BDIM * KDIM / 4)
#define W_CHUNKS  ((int64_t)3 * HDIM * KDIM / 4)

__global__ void cvt_all_kernel(const float* __restrict__ x,
                               const float* __restrict__ h,
                               const float* __restrict__ Wf,
                               const float* __restrict__ Wo,
                               const float* __restrict__ Wc,
                               uint16_t* __restrict__ xh,
                               uint16_t* __restrict__ Wb) {
    const int64_t total = XH_CHUNKS + W_CHUNKS;
    for (int64_t i = (int64_t)blockIdx.x * blockDim.x + threadIdx.x; i < total;
         i += (int64_t)gridDim.x * blockDim.x) {
        float4 v;
        uint16_t* dst;
        if (i < XH_CHUNKS) {
            int64_t e = i << 2;
            int b = (int)(e >> 12);
            int k = (int)(e & 4095);
            if (k < 2048) v = *(const float4*)(x + (int64_t)b * 2048 + k);
            else          v = *(const float4*)(h + (int64_t)b * 2048 + (k - 2048));
            dst = xh + e;
        } else {
            int64_t e = (i - XH_CHUNKS) << 2;
            const int64_t per_gate = (int64_t)HDIM * KDIM;
            int gate = (int)(e / per_gate);
            int64_t rem = e - (int64_t)gate * per_gate;
            const float* src = (gate == 0) ? Wf : (gate == 1) ? Wo : Wc;
            v = *(const float4*)(src + rem);
            dst = Wb + e;
        }
        ushort4 o;
        o.x = f2bf(v.x); o.y = f2bf(v.y); o.z = f2bf(v.z); o.w = f2bf(v.w);
        *(ushort4*)dst = o;
    }
}

// ---------------- 256x256 8-phase GEMM (single-barrier phases) -----------
// Identical ring/read/stage/wait mapping to round 5; barrier#1 removed.
// Safety: (1) staged-data publish = issuer vmcnt (WC*) + end-barrier, kept.
// (2) re-stage of any slot is >=1 phase after its last read; readers'
// ds_reads complete before their own MFMA (compiler lgkm waits) which
// precedes their end-barrier arrival, which precedes any wave's next-phase
// stage issue. So no read/overwrite race without barrier#1.
// Phase reads: P1 aF(t0,h0)(8) P2 bF1(t0,h1)(4) P3 aF(t0,h1)(8) P4 bF0(t1,h0)(4)
//              P5 aF(t1,h0)    P6 bF1(t1,h1)    P7 aF(t1,h1)    P8 bF0(t2,h0)
// Stage order: P1->s3, P2->s0, P3->s4, P4->s1, P5->s5, P6->s2, P7->s6, P8->s7
// Waits: WC6@P3, WC4@P4, WC6@P7, WC4@P8 (coverage proof in round-5 header).

#define STAGE_A(slot, t, h) do { \
    _Pragma("unroll") for (int q_ = 0; q_ < 2; ++q_) { \
        const int r_ = s_row[q_]; \
        const uint16_t* src_ = A + (int64_t)(m0 + ((r_ >> 6) << 7) + ((h) << 6) + (r_ & 63)) * KDIM + ((t) << 6) + s_kc[q_]; \
        __builtin_amdgcn_global_load_lds((__attribute__((address_space(1))) void*)(src_), \
            (__attribute__((address_space(3))) void*)(&lds[slot][(q_ * 512 + tid) * 8]), 16, 0, 0); \
    } } while (0)

#define STAGE_B(slot, t, h) do { \
    _Pragma("unroll") for (int q_ = 0; q_ < 2; ++q_) { \
        const int r_ = s_row[q_]; \
        const uint16_t* src_ = Wb + (int64_t)(n0 + ((r_ >> 5) << 6) + ((h) << 5) + (r_ & 31)) * KDIM + ((t) << 6) + s_kc[q_]; \
        __builtin_amdgcn_global_load_lds((__attribute__((address_space(1))) void*)(src_), \
            (__attribute__((address_space(3))) void*)(&lds[slot][(q_ * 512 + tid) * 8]), 16, 0, 0); \
    } } while (0)

// read logical (slot, srow, kchunk) with swizzle
#define RD(slot, srow, kc) \
    (*(const bf16x8*)((const char*)(&lds[0][0]) + ((slot) * 16384) + ((srow) * 128) + ((((kc) ^ ((srow) & 7))) * 16)))

#define RD_A(tp, h) do { \
    _Pragma("unroll") for (int kk = 0; kk < 2; ++kk) \
        _Pragma("unroll") for (int mf = 0; mf < 4; ++mf) \
            aF[kk][mf] = RD((((tp) & 1) << 1) + (h), wm * 64 + mf * 16 + fr, kk * 4 + kg); \
} while (0)

#define RD_B(dst, tp, h) do { \
    _Pragma("unroll") for (int kk = 0; kk < 2; ++kk) \
        _Pragma("unroll") for (int nf = 0; nf < 2; ++nf) \
            dst[kk][nf] = RD(4 + (((tp) & 1) << 1) + (h), wn * 32 + nf * 16 + fr, kk * 4 + kg); \
} while (0)

#define MM(qm, qn, bsrc) do { \
    _Pragma("unroll") for (int kk = 0; kk < 2; ++kk) \
        _Pragma("unroll") for (int mf = 0; mf < 4; ++mf) \
            _Pragma("unroll") for (int nf = 0; nf < 2; ++nf) \
                acc[(qm) * 4 + mf][(qn) * 2 + nf] = __builtin_amdgcn_mfma_f32_16x16x32_bf16( \
                    aF[kk][mf], bsrc[kk][nf], acc[(qm) * 4 + mf][(qn) * 2 + nf], 0, 0, 0); \
} while (0)

#define PHX(READS, STAGE, MFMAS, WAITC) do { \
    asm volatile("" ::: "memory"); \
    READS; \
    STAGE; \
    asm volatile("" ::: "memory"); \
    __builtin_amdgcn_s_setprio(1); \
    MFMAS; \
    __builtin_amdgcn_s_setprio(0); \
    WAITC; \
    __builtin_amdgcn_s_barrier(); \
} while (0)

#define WC6 asm volatile("s_waitcnt vmcnt(6)" ::: "memory")
#define WC4 asm volatile("s_waitcnt vmcnt(4)" ::: "memory")
#define WC0 asm volatile("s_waitcnt vmcnt(0)" ::: "memory")

__global__ __launch_bounds__(512, 2) void lstm_gemm8p_kernel(
    const uint16_t* __restrict__ A,
    const uint16_t* __restrict__ Wb,
    uint16_t* __restrict__ G) {
    __shared__ uint16_t lds[8][8192];  // 128 KiB

    const int tid = threadIdx.x;
    const int lane = tid & 63;
    const int kg = lane >> 4;
    const int fr = lane & 15;
    const int wid = tid >> 6;
    const int wm = wid >> 2;   // 0..1
    const int wn = wid & 3;    // 0..3

    // XCD-aware swizzle: 768 blocks, 768 % 8 == 0 -> simple bijection
    const int bid = blockIdx.x;
    const int swz = (bid & 7) * 96 + (bid >> 3);
    const int mb = swz / 24;
    const int nb = swz - mb * 24;
    const int m0 = mb << 8;
    const int n0 = nb << 8;

    // staging constants: chunk = q*512 + tid -> row, swizzled k-chunk
    int s_row[2], s_kc[2];
#pragma unroll
    for (int q_ = 0; q_ < 2; ++q_) {
        const int chunk = q_ * 512 + tid;
        const int r_ = chunk >> 3;
        const int c_ = chunk & 7;
        s_row[q_] = r_;
        s_kc[q_] = (c_ ^ (r_ & 7)) * 8;  // element offset
    }

    f32x4 acc[8][4] = {};
    bf16x8 aF[2][4];
    bf16x8 bF0[2][2];
    bf16x8 bF1[2][2];

    // prologue: t0 full (s0,s4,s1,s5), t1 h0 (s2,s6), t1 h1 B (s7).
    STAGE_A(0, 0, 0); STAGE_B(4, 0, 0);
    STAGE_A(1, 0, 1); STAGE_B(5, 0, 1);
    STAGE_A(2, 1, 0); STAGE_B(6, 1, 0);
    STAGE_B(7, 1, 1);
    WC4;  // completes s0,s4,s1,s5,s2 ; leaves s6,s7 in flight
    __builtin_amdgcn_s_barrier();
    RD_B(bF0, 0, 0);  // pre-read B(t0,h0) from s4 (complete; all waves waited)

    // 64 K-tiles, 2 per iteration; i=31 is the peeled tail
    for (int i = 0; i < 31; ++i) {
        const int t0 = 2 * i;
        const int t1 = t0 + 1, t2 = t0 + 2, t3 = t0 + 3;
        PHX(RD_A(t0, 0),      STAGE_A(3, t1, 1), MM(0, 0, bF0), );
        PHX(RD_B(bF1, t0, 1), STAGE_A(0, t2, 0), MM(0, 1, bF1), );
        PHX(RD_A(t0, 1),      STAGE_B(4, t2, 0), MM(1, 0, bF0), WC6);
        PHX(RD_B(bF0, t1, 0), STAGE_A(1, t2, 1), MM(1, 1, bF1), WC4);
        PHX(RD_A(t1, 0),      STAGE_B(5, t2, 1), MM(0, 0, bF0), );
        PHX(RD_B(bF1, t1, 1), STAGE_A(2, t3, 0), MM(0, 1, bF1), );
        PHX(RD_A(t1, 1),      STAGE_B(6, t3, 0), MM(1, 0, bF0), WC6);
        PHX(RD_B(bF0, t2, 0), STAGE_B(7, t3, 1), MM(1, 1, bF1), WC4);
    }
    // tail: t0=62, t1=63; only the s3 stage remains in-range
    PHX(RD_A(62, 0),      STAGE_A(3, 63, 1), MM(0, 0, bF0), );
    PHX(RD_B(bF1, 62, 1), ;,                 MM(0, 1, bF1), );
    PHX(RD_A(62, 1),      ;,                 MM(1, 0, bF0), WC0);
    PHX(RD_B(bF0, 63, 0), ;,                 MM(1, 1, bF1), );
    PHX(RD_A(63, 0),      ;,                 MM(0, 0, bF0), );
    PHX(RD_B(bF1, 63, 1), ;,                 MM(0, 1, bF1), );
    PHX(RD_A(63, 1),      ;,                 MM(1, 0, bF0), );
    PHX(;,                ;,                 MM(1, 1, bF1), );

    // C-write: D layout col = lane&15, row = (lane>>4)*4 + j
#pragma unroll
    for (int mf = 0; mf < 8; ++mf) {
#pragma unroll
        for (int nf = 0; nf < 4; ++nf) {
            const int n = n0 + wn * 64 + nf * 16 + fr;
            const int64_t mbase = (int64_t)(m0 + wm * 128 + mf * 16 + kg * 4);
#pragma unroll
            for (int j = 0; j < 4; ++j) {
                G[(mbase + j) * NDIM + n] = f2bf(acc[mf][nf][j]);
            }
        }
    }
}

// ---------------- LSTM elementwise epilogue ----------------

__global__ void lstm_epi_kernel(const uint16_t* __restrict__ G,
                                const float* __restrict__ c_prev,
                                const float* __restrict__ b_f,
                                const float* __restrict__ b_o,
                                const float* __restrict__ b_c,
                                float* __restrict__ h_out,
                                float* __restrict__ c_out) {
    const int64_t total = (int64_t)BDIM * HDIM / 8;
    for (int64_t i = (int64_t)blockIdx.x * blockDim.x + threadIdx.x; i < total;
         i += (int64_t)gridDim.x * blockDim.x) {
        const int64_t e = i << 3;
        const int m = (int)(e >> 11);
        const int n = (int)(e & 2047);
        const int64_t gb = (int64_t)m * NDIM + n;
        const short8 fv = *(const short8*)(G + gb);
        const short8 ov = *(const short8*)(G + gb + HDIM);
        const short8 cv = *(const short8*)(G + gb + 2 * HDIM);
        const float4 cp0 = *(const float4*)(c_prev + (int64_t)m * HDIM + n);
        const float4 cp1 = *(const float4*)(c_prev + (int64_t)m * HDIM + n + 4);
        float cp[8] = {cp0.x, cp0.y, cp0.z, cp0.w, cp1.x, cp1.y, cp1.z, cp1.w};
        float hr[8], cr[8];
#pragma unroll
        for (int j = 0; j < 8; ++j) {
            const float fpre = bf2f((uint16_t)fv[j]) + b_f[n + j];
            const float opre = bf2f((uint16_t)ov[j]) + b_o[n + j];
            const float cpre = bf2f((uint16_t)cv[j]) + b_c[n + j];
            const float ft = fast_sigmoid(fpre);
            const float ot = fast_sigmoid(opre);
            const float ch = fast_tanh(cpre);
            const float ct = ft * cp[j] + (1.0f - ft) * ch;
            hr[j] = ot * fast_tanh(ct);
            cr[j] = ct;
        }
        float4 h0 = {hr[0], hr[1], hr[2], hr[3]};
        float4 h1 = {hr[4], hr[5], hr[6], hr[7]};
        float4 c0 = {cr[0], cr[1], cr[2], cr[3]};
        float4 c1 = {cr[4], cr[5], cr[6], cr[7]};
        *(float4*)(h_out + (int64_t)m * HDIM + n) = h0;
        *(float4*)(h_out + (int64_t)m * HDIM + n + 4) = h1;
        *(float4*)(c_out + (int64_t)m * HDIM + n) = c0;
        *(float4*)(c_out + (int64_t)m * HDIM + n + 4) = c1;
    }
}

extern "C" void kernel_launch(void* const* d_in, const int* in_sizes, int n_in,
                              void* d_out, int out_size, void* d_ws, size_t ws_size,
                              hipStream_t stream) {
    const float* x_t   = (const float*)d_in[0];
    const float* h_t_1 = (const float*)d_in[1];
    const float* c_t_1 = (const float*)d_in[2];
    const float* W_f   = (const float*)d_in[3];
    const float* b_f   = (const float*)d_in[4];
    const float* W_o   = (const float*)d_in[5];
    const float* b_o   = (const float*)d_in[6];
    const float* W_c   = (const float*)d_in[7];
    const float* b_c   = (const float*)d_in[8];

    uint16_t* xh  = (uint16_t*)d_ws;                            // 64 MiB
    uint16_t* Wbf = xh + (size_t)BDIM * KDIM;                   // 48 MiB
    uint16_t* G   = Wbf + (size_t)NDIM * KDIM;                  // 96 MiB

    float* h_out = (float*)d_out;
    float* c_out = h_out + (size_t)BDIM * HDIM;

    cvt_all_kernel<<<2048, 256, 0, stream>>>(x_t, h_t_1, W_f, W_o, W_c, xh, Wbf);
    lstm_gemm8p_kernel<<<768, 512, 0, stream>>>(xh, Wbf, G);
    lstm_epi_kernel<<<2048, 256, 0, stream>>>(G, c_t_1, b_f, b_o, b_c,
                                              h_out, c_out);
}